// Round 5
// baseline (52.597 us; speedup 1.0000x reference)
//
#include <hip/hip_runtime.h>
#include <hip/hip_bf16.h>
#include <math.h>

#define BB 64
#define LL 512
#define HH 768
#define SS 32
#define MM 2048
#define EPS_LN 1e-12f
#define EPS_COS 1e-8f

#define NKS 24                 // k-steps of 32
#define NGB 384                // gemm blocks (64m x 64n tiles: 32 x 12)
#define GP_BLK 768             // gp convert blocks (2048 elems each)
#define W_BLK 288              // W convert blocks
#define SEG_SLICES 8
#define SEG_BLK (BB * SEG_SLICES)   // 512

typedef __attribute__((ext_vector_type(8))) short short8;
typedef __attribute__((ext_vector_type(4))) float f32x4;

static __device__ inline unsigned short f2bf(float x) {
    __hip_bfloat16 h = __float2bfloat16(x);
    unsigned short b; __builtin_memcpy(&b, &h, 2); return b;
}
static __device__ inline float bf2f(unsigned short b) {
    __hip_bfloat16 h; __builtin_memcpy(&h, &b, 2); return __bfloat162float(h);
}

// flat coalesced split: 8 consecutive elements per thread
static __device__ inline void split8(const float* __restrict__ src,
                                     unsigned short* __restrict__ hi,
                                     unsigned short* __restrict__ lo, size_t e) {
    float xv[8];
    *(float4*)&xv[0] = *(const float4*)(src + e);
    *(float4*)&xv[4] = *(const float4*)(src + e + 4);
    union { unsigned short u[8]; short8 v; } Hc, Lc;
#pragma unroll
    for (int j = 0; j < 8; ++j) {
        const unsigned short hb = f2bf(xv[j]);
        Hc.u[j] = hb;
        Lc.u[j] = f2bf(xv[j] - bf2f(hb));
    }
    *(short8*)(hi + e) = Hc.v;
    *(short8*)(lo + e) = Lc.v;
}

// K1: [0,768) split gp; [768,1056) split W; [1056,1568) segmean partials (8 L-slices).
__global__ __launch_bounds__(256) void k_prep(
    const float* __restrict__ gp, const float* __restrict__ Wm,
    const float* __restrict__ hs,
    const int* __restrict__ gstart, const int* __restrict__ gend,
    unsigned short* __restrict__ ah, unsigned short* __restrict__ al,
    unsigned short* __restrict__ bh, unsigned short* __restrict__ bl,
    float* __restrict__ pp)         // [BB][SEG_SLICES][HH] partial sums
{
    const int bid = blockIdx.x;
    const int t = threadIdx.x;

    if (bid < GP_BLK) {
        split8(gp, ah, al, (size_t)bid * 2048 + t * 8);
    } else if (bid < GP_BLK + W_BLK) {
        split8(Wm, bh, bl, (size_t)(bid - GP_BLK) * 2048 + t * 8);
    } else {
        const int id = bid - (GP_BLK + W_BLK);
        const int b = id >> 3;
        const int sl = id & 7;
        const int s0 = gstart[b], e0 = gend[b];
        const int lo = max(s0, sl * 64);
        const int hi = min(e0, sl * 64 + 64);
        const float* base = hs + (size_t)b * LL * HH;
        const int c0 = t, c1 = t + 256, c2 = t + 512;
        float a[3][4];
#pragma unroll
        for (int j = 0; j < 3; ++j)
#pragma unroll
            for (int u = 0; u < 4; ++u) a[j][u] = 0.f;
        int l = lo;
        for (; l + 4 <= hi; l += 4) {
#pragma unroll
            for (int u = 0; u < 4; ++u) {
                const float* row = base + (size_t)(l + u) * HH;
                a[0][u] += row[c0]; a[1][u] += row[c1]; a[2][u] += row[c2];
            }
        }
        for (; l < hi; ++l) {
            const float* row = base + (size_t)l * HH;
            a[0][0] += row[c0]; a[1][0] += row[c1]; a[2][0] += row[c2];
        }
        float* dst = pp + (size_t)id * HH;
        dst[c0] = (a[0][0] + a[0][1]) + (a[0][2] + a[0][3]);
        dst[c1] = (a[1][0] + a[1][1]) + (a[1][2] + a[1][3]);
        dst[c2] = (a[2][0] + a[2][1]) + (a[2][2] + a[2][3]);
    }
}

// K2: gemm blocks [0,384): t = gp @ W^T, 3-term bf16-split MFMA, no LDS.
//     combine blocks [384,448): sum segmean partials + LN(g2,b2) -> sel, selnorm.
#define TRI(ACC, AH_, AL_, BH_, BL_) \
    ACC = __builtin_amdgcn_mfma_f32_16x16x32_bf16(AH_, BH_, ACC, 0, 0, 0); \
    ACC = __builtin_amdgcn_mfma_f32_16x16x32_bf16(AH_, BL_, ACC, 0, 0, 0); \
    ACC = __builtin_amdgcn_mfma_f32_16x16x32_bf16(AL_, BH_, ACC, 0, 0, 0);

#define DECLSET(P) short8 P##a0h,P##a0l,P##a1h,P##a1l, \
    P##b0h,P##b0l,P##b1h,P##b1l,P##b2h,P##b2l,P##b3h,P##b3l;

#define LOADSET(P, KS) { const int o_ = (KS) * 32; \
    P##a0h = *(const short8*)(pa0h + o_); P##a0l = *(const short8*)(pa0l + o_); \
    P##a1h = *(const short8*)(pa1h + o_); P##a1l = *(const short8*)(pa1l + o_); \
    P##b0h = *(const short8*)(pb0h + o_); P##b0l = *(const short8*)(pb0l + o_); \
    P##b1h = *(const short8*)(pb1h + o_); P##b1l = *(const short8*)(pb1l + o_); \
    P##b2h = *(const short8*)(pb2h + o_); P##b2l = *(const short8*)(pb2l + o_); \
    P##b3h = *(const short8*)(pb3h + o_); P##b3l = *(const short8*)(pb3l + o_); }

#define MFMASET(P) \
    TRI(acc[0][0], P##a0h, P##a0l, P##b0h, P##b0l) \
    TRI(acc[0][1], P##a0h, P##a0l, P##b1h, P##b1l) \
    TRI(acc[0][2], P##a0h, P##a0l, P##b2h, P##b2l) \
    TRI(acc[0][3], P##a0h, P##a0l, P##b3h, P##b3l) \
    TRI(acc[1][0], P##a1h, P##a1l, P##b0h, P##b0l) \
    TRI(acc[1][1], P##a1h, P##a1l, P##b1h, P##b1l) \
    TRI(acc[1][2], P##a1h, P##a1l, P##b2h, P##b2l) \
    TRI(acc[1][3], P##a1h, P##a1l, P##b3h, P##b3l)

__global__ __launch_bounds__(128) void k_gemm(
    const unsigned short* __restrict__ ah, const unsigned short* __restrict__ al,
    const unsigned short* __restrict__ bh, const unsigned short* __restrict__ bl,
    const float* __restrict__ pp,
    const float* __restrict__ g2, const float* __restrict__ b2,
    const int* __restrict__ gstart, const int* __restrict__ gend,
    float* __restrict__ tbuf, float* __restrict__ sel, float* __restrict__ selnorm)
{
    __shared__ float red[2][2], red2[2], sh2[2];

    if (blockIdx.x < NGB) {
        const int orig = blockIdx.x;
        const int bid = (orig & 7) * 48 + (orig >> 3);   // XCD swizzle (384 % 8 == 0)
        const int mb = bid / 12;
        const int nb = bid - mb * 12;
        const int wave = threadIdx.x >> 6;
        const int lane = threadIdx.x & 63;

        const int mg0 = mb * 4 + wave * 2;
        const int ng0 = nb * 4;
        const int r = lane & 15;
        const int kq = (lane >> 4) * 8;

        const size_t offA = (size_t)(mg0 * 16 + r) * HH + kq;
        const unsigned short* pa0h = ah + offA;
        const unsigned short* pa0l = al + offA;
        const unsigned short* pa1h = pa0h + 16 * HH;
        const unsigned short* pa1l = pa0l + 16 * HH;
        const size_t offB = (size_t)(ng0 * 16 + r) * HH + kq;
        const unsigned short* pb0h = bh + offB;
        const unsigned short* pb0l = bl + offB;
        const unsigned short* pb1h = pb0h + 16 * HH;
        const unsigned short* pb1l = pb0l + 16 * HH;
        const unsigned short* pb2h = pb1h + 16 * HH;
        const unsigned short* pb2l = pb1l + 16 * HH;
        const unsigned short* pb3h = pb2h + 16 * HH;
        const unsigned short* pb3l = pb2l + 16 * HH;

        f32x4 acc[2][4] = {};
        DECLSET(A) DECLSET(B) DECLSET(C)

        LOADSET(A, 0)
        LOADSET(B, 1)
        for (int ks = 0; ks <= 18; ks += 3) {
            LOADSET(C, ks + 2)
            MFMASET(A)
            LOADSET(A, ks + 3)
            MFMASET(B)
            LOADSET(B, ks + 4)
            MFMASET(C)
        }
        LOADSET(C, 23)
        MFMASET(A)
        MFMASET(B)
        MFMASET(C)

        const int wm = mg0 * 16;
        const int wn = nb * 64;
        const int r0 = (lane >> 4) * 4;
        const int cc = lane & 15;
#pragma unroll
        for (int mi = 0; mi < 2; ++mi)
#pragma unroll
            for (int ni = 0; ni < 4; ++ni)
#pragma unroll
                for (int j = 0; j < 4; ++j)
                    tbuf[(size_t)(wm + mi * 16 + r0 + j) * HH + wn + ni * 16 + cc] =
                        acc[mi][ni][j];
    } else {
        // -------- combine segmean partials + LN(g2,b2) --------
        const int cb = blockIdx.x - NGB;
        const int t = threadIdx.x;
        const int lane = t & 63, wv = t >> 6;
        const int s0 = gstart[cb], e0 = gend[cb];
        const float inv = 1.0f / fmaxf((float)(e0 - s0), 1.0f);

        float v[6];
#pragma unroll
        for (int j = 0; j < 6; ++j) v[j] = 0.f;
        const float* base = pp + (size_t)cb * SEG_SLICES * HH;
#pragma unroll
        for (int sl = 0; sl < SEG_SLICES; ++sl) {
#pragma unroll
            for (int j = 0; j < 6; ++j)
                v[j] += base[(size_t)sl * HH + t + 128 * j];
        }
        float s = 0.f, q = 0.f;
#pragma unroll
        for (int j = 0; j < 6; ++j) {
            v[j] *= inv;
            s += v[j];
            q = fmaf(v[j], v[j], q);
        }
        for (int o = 32; o > 0; o >>= 1) {
            s += __shfl_xor(s, o, 64);
            q += __shfl_xor(q, o, 64);
        }
        if (lane == 0) { red[0][wv] = s; red[1][wv] = q; }
        __syncthreads();
        if (t == 0) {
            const float ts = red[0][0] + red[0][1];
            const float tq = red[1][0] + red[1][1];
            const float mu = ts / (float)HH;
            const float var = tq / (float)HH - mu * mu;
            sh2[0] = mu;
            sh2[1] = rsqrtf(var + EPS_LN);
        }
        __syncthreads();
        const float mu = sh2[0], rinv = sh2[1];
        float n = 0.f;
#pragma unroll
        for (int j = 0; j < 6; ++j) {
            const int c = t + 128 * j;
            const float y = (v[j] - mu) * rinv * g2[c] + b2[c];
            sel[(size_t)cb * HH + c] = y;
            n = fmaf(y, y, n);
        }
        for (int o = 32; o > 0; o >>= 1) n += __shfl_xor(n, o, 64);
        if (lane == 0) red2[wv] = n;
        __syncthreads();
        if (t == 0) selnorm[cb] = sqrtf(red2[0] + red2[1]);
    }
}

// K3: per-row LN(g1,b1) + cosine vs sel. One wave per t-row; bias folded in.
__global__ __launch_bounds__(512) void k_finish(
    const float* __restrict__ tbuf, const float* __restrict__ bias,
    const float* __restrict__ g1, const float* __restrict__ b1,
    const float* __restrict__ sel, const float* __restrict__ selnorm,
    float* __restrict__ out)
{
    const int lane = threadIdx.x & 63;
    const int w = threadIdx.x >> 6;
    const int m = blockIdx.x * 8 + w;
    const int b = m >> 5;
    const float* trow = tbuf + (size_t)m * HH;

    float v[12];
#pragma unroll
    for (int j = 0; j < 12; ++j) {
        const int col = lane + 64 * j;
        v[j] = trow[col] + bias[col];
    }
    float s = 0.f, q = 0.f;
#pragma unroll
    for (int j = 0; j < 12; ++j) { s += v[j]; q = fmaf(v[j], v[j], q); }
    for (int o = 32; o > 0; o >>= 1) {
        s += __shfl_xor(s, o, 64);
        q += __shfl_xor(q, o, 64);
    }
    const float mu = s * (1.0f / (float)HH);
    const float var = q * (1.0f / (float)HH) - mu * mu;
    const float rinv = rsqrtf(var + EPS_LN);

    const float* selb = sel + (size_t)b * HH;
    float d = 0.f, n2 = 0.f;
#pragma unroll
    for (int j = 0; j < 12; ++j) {
        const int col = lane + 64 * j;
        const float y = (v[j] - mu) * rinv * g1[col] + b1[col];
        d = fmaf(y, selb[col], d);
        n2 = fmaf(y, y, n2);
    }
    for (int o = 32; o > 0; o >>= 1) {
        d += __shfl_xor(d, o, 64);
        n2 += __shfl_xor(n2, o, 64);
    }
    if (lane == 0)
        out[m] = d / fmaxf(selnorm[b] * sqrtf(n2), EPS_COS);
}

extern "C" void kernel_launch(void* const* d_in, const int* in_sizes, int n_in,
                              void* d_out, int out_size, void* d_ws, size_t ws_size,
                              hipStream_t stream) {
    const float* hs  = (const float*)d_in[0];
    const float* gp  = (const float*)d_in[1];
    const float* W   = (const float*)d_in[2];
    const float* bia = (const float*)d_in[3];
    const float* g1  = (const float*)d_in[4];
    const float* b1  = (const float*)d_in[5];
    const float* g2  = (const float*)d_in[6];
    const float* b2  = (const float*)d_in[7];
    const int* gs    = (const int*)d_in[8];
    const int* ge    = (const int*)d_in[9];
    float* out = (float*)d_out;

    char* ws = (char*)d_ws;
    unsigned short* ah = (unsigned short*)ws;                       // 3.15 MB
    unsigned short* al = ah + (size_t)MM * HH;                      // 3.15 MB
    unsigned short* bh = al + (size_t)MM * HH;                      // 1.18 MB
    unsigned short* bl = bh + (size_t)HH * HH;                      // 1.18 MB
    float* tbuf    = (float*)(bl + (size_t)HH * HH);                // 6.29 MB
    float* pp      = tbuf + (size_t)MM * HH;                        // 1.57 MB
    float* sel     = pp + (size_t)BB * SEG_SLICES * HH;             // 0.20 MB
    float* selnorm = sel + (size_t)BB * HH;

    k_prep<<<GP_BLK + W_BLK + SEG_BLK, 256, 0, stream>>>(gp, W, hs, gs, ge,
                                                         ah, al, bh, bl, pp);
    k_gemm<<<NGB + BB, 128, 0, stream>>>(ah, al, bh, bl, pp, g2, b2, gs, ge,
                                         tbuf, sel, selnorm);
    k_finish<<<MM / 8, 512, 0, stream>>>(tbuf, bia, g1, b1, sel, selnorm, out);
}

// Round 6
// 33.328 us; speedup vs baseline: 1.5782x; 1.5782x over previous
//
#include <hip/hip_runtime.h>
#include <hip/hip_bf16.h>
#include <math.h>

#define BB 64
#define LL 512
#define HH 768
#define SS 32
#define MM 2048
#define EPS_LN 1e-12f
#define EPS_COS 1e-8f

#define NKS 24                 // k-steps of 32
#define NGB 384                // gemm blocks (64m x 64n tiles: 32 x 12)
#define CH_PER_G (NKS * 2 * 64) // short8 chunks per row-group
#define SEG_SLICES 8
#define SEG_BLK (BB * SEG_SLICES)    // 512
#define A_RG (MM / 16)               // 128
#define B_RG (HH / 16)               // 48
#define LDST 772                     // LDS row stride (floats): 16B-aligned, spreads banks

typedef __attribute__((ext_vector_type(8))) short short8;
typedef __attribute__((ext_vector_type(4))) float f32x4;

static __device__ inline unsigned short f2bf(float x) {
    __hip_bfloat16 h = __float2bfloat16(x);
    unsigned short b; __builtin_memcpy(&b, &h, 2); return b;
}
static __device__ inline float bf2f(unsigned short b) {
    __hip_bfloat16 h; __builtin_memcpy(&h, &b, 2); return __bfloat162float(h);
}

// K1: bid [0,512): segmean partials (slice sl of batch b, early dispatch);
//     bid [512,640): split gp row-group;  [640,688): split W row-group.
// Fragment-linear output chunk: dst[((rg*NKS+ks)*2+plane)*64 + lane], lane l
// holds row rg*16+(l&15), k = ks*32+(l>>4)*8 .. +8.
__global__ __launch_bounds__(256) void k_prep(
    const float* __restrict__ gp, const float* __restrict__ Wm,
    const float* __restrict__ hs,
    const int* __restrict__ gstart, const int* __restrict__ gend,
    short8* __restrict__ a_ws, short8* __restrict__ b_ws,
    float* __restrict__ pp)         // [BB][SEG_SLICES][HH] partial sums
{
    __shared__ __align__(16) float xs[16][LDST];   // 49.4 KB
    const int bid = blockIdx.x;
    const int t = threadIdx.x;

    if (bid < SEG_BLK) {
        const int b = bid >> 3;
        const int sl = bid & 7;
        const int s0 = gstart[b], e0 = gend[b];
        const int lo = max(s0, sl * 64);
        const int hi = min(e0, sl * 64 + 64);
        const float* base = hs + (size_t)b * LL * HH;
        const int c0 = t, c1 = t + 256, c2 = t + 512;
        float a[3][4];
#pragma unroll
        for (int j = 0; j < 3; ++j)
#pragma unroll
            for (int u = 0; u < 4; ++u) a[j][u] = 0.f;
        int l = lo;
        for (; l + 4 <= hi; l += 4) {
#pragma unroll
            for (int u = 0; u < 4; ++u) {
                const float* row = base + (size_t)(l + u) * HH;
                a[0][u] += row[c0]; a[1][u] += row[c1]; a[2][u] += row[c2];
            }
        }
        for (; l < hi; ++l) {
            const float* row = base + (size_t)l * HH;
            a[0][0] += row[c0]; a[1][0] += row[c1]; a[2][0] += row[c2];
        }
        float* dst = pp + (size_t)bid * HH;
        dst[c0] = (a[0][0] + a[0][1]) + (a[0][2] + a[0][3]);
        dst[c1] = (a[1][0] + a[1][1]) + (a[1][2] + a[1][3]);
        dst[c2] = (a[2][0] + a[2][1]) + (a[2][2] + a[2][3]);
    } else {
        const bool isA = bid < SEG_BLK + A_RG;
        const int rg = isA ? (bid - SEG_BLK) : (bid - SEG_BLK - A_RG);
        const float* src = (isA ? gp : Wm) + (size_t)rg * 16 * HH;
        short8* dst = isA ? a_ws : b_ws;

        // coalesced stage: 16 rows x 768 floats, contiguous in global
#pragma unroll
        for (int j = 0; j < 12; ++j) {
            const int idx = t + j * 256;        // 0..3071 float4s
            const int row = idx / 192;
            const int col = (idx - row * 192) * 4;
            *(float4*)&xs[row][col] = *(const float4*)(src + (size_t)idx * 4);
        }
        __syncthreads();

        const int l = t & 63;
        const int cslot = t >> 6;               // 0..3
        const int row = l & 15;
        const int kq = (l >> 4) * 8;
#pragma unroll
        for (int i = 0; i < 6; ++i) {
            const int ks = i * 4 + cslot;
            float xv[8];
            *(float4*)&xv[0] = *(const float4*)&xs[row][ks * 32 + kq];
            *(float4*)&xv[4] = *(const float4*)&xs[row][ks * 32 + kq + 4];
            union { unsigned short u[8]; short8 v; } Hc, Lc;
#pragma unroll
            for (int j = 0; j < 8; ++j) {
                const unsigned short hb = f2bf(xv[j]);
                Hc.u[j] = hb;
                Lc.u[j] = f2bf(xv[j] - bf2f(hb));
            }
            dst[((size_t)(rg * NKS + ks) * 2) * 64 + l]     = Hc.v;
            dst[((size_t)(rg * NKS + ks) * 2 + 1) * 64 + l] = Lc.v;
        }
    }
}

// K2: blocks [0,384): t = gp @ W^T via 3-term bf16-split MFMA, no LDS, no barriers
//     (fragment-linear operands: every wave load = 64 lanes x 16B contiguous).
//     blocks [384,448): combine segmean partials + LN(g2,b2) -> sel, selnorm.
#define TRI(ACC, AH_, AL_, BH_, BL_) \
    ACC = __builtin_amdgcn_mfma_f32_16x16x32_bf16(AH_, BH_, ACC, 0, 0, 0); \
    ACC = __builtin_amdgcn_mfma_f32_16x16x32_bf16(AH_, BL_, ACC, 0, 0, 0); \
    ACC = __builtin_amdgcn_mfma_f32_16x16x32_bf16(AL_, BH_, ACC, 0, 0, 0);

#define DECLSET(P) short8 P##a0h,P##a0l,P##a1h,P##a1l, \
    P##b0h,P##b0l,P##b1h,P##b1l,P##b2h,P##b2l,P##b3h,P##b3l;

#define LOADSET(P, KS) { const int o_ = (KS) * 128; \
    P##a0h = ba0[o_]; P##a0l = ba0[o_ + 64]; P##a1h = ba1[o_]; P##a1l = ba1[o_ + 64]; \
    P##b0h = bb0[o_]; P##b0l = bb0[o_ + 64]; P##b1h = bb1[o_]; P##b1l = bb1[o_ + 64]; \
    P##b2h = bb2[o_]; P##b2l = bb2[o_ + 64]; P##b3h = bb3[o_]; P##b3l = bb3[o_ + 64]; }

#define MFMASET(P) \
    TRI(acc[0][0], P##a0h, P##a0l, P##b0h, P##b0l) \
    TRI(acc[0][1], P##a0h, P##a0l, P##b1h, P##b1l) \
    TRI(acc[0][2], P##a0h, P##a0l, P##b2h, P##b2l) \
    TRI(acc[0][3], P##a0h, P##a0l, P##b3h, P##b3l) \
    TRI(acc[1][0], P##a1h, P##a1l, P##b0h, P##b0l) \
    TRI(acc[1][1], P##a1h, P##a1l, P##b1h, P##b1l) \
    TRI(acc[1][2], P##a1h, P##a1l, P##b2h, P##b2l) \
    TRI(acc[1][3], P##a1h, P##a1l, P##b3h, P##b3l)

__global__ __launch_bounds__(128) void k_gemm(
    const short8* __restrict__ aw, const short8* __restrict__ bw,
    const float* __restrict__ pp,
    const float* __restrict__ g2, const float* __restrict__ b2,
    const int* __restrict__ gstart, const int* __restrict__ gend,
    float* __restrict__ tbuf, float* __restrict__ sel, float* __restrict__ selnorm)
{
    __shared__ float red[2][2], red2[2], sh2[2];

    if (blockIdx.x < NGB) {
        const int orig = blockIdx.x;
        const int bid = (orig & 7) * 48 + (orig >> 3);   // XCD swizzle (384 % 8 == 0)
        const int mb = bid / 12;
        const int nb = bid - mb * 12;
        const int wave = threadIdx.x >> 6;
        const int lane = threadIdx.x & 63;

        const int mg0 = mb * 4 + wave * 2;
        const short8* ba0 = aw + (size_t)mg0 * CH_PER_G + lane;
        const short8* ba1 = ba0 + CH_PER_G;
        const short8* bb0 = bw + (size_t)(nb * 4) * CH_PER_G + lane;
        const short8* bb1 = bb0 + CH_PER_G;
        const short8* bb2 = bb1 + CH_PER_G;
        const short8* bb3 = bb2 + CH_PER_G;

        f32x4 acc[2][4] = {};
        DECLSET(A) DECLSET(C)

        LOADSET(A, 0)
        for (int ks = 0; ks < NKS - 2; ks += 2) {
            LOADSET(C, ks + 1)
            MFMASET(A)
            LOADSET(A, ks + 2)
            MFMASET(C)
        }
        LOADSET(C, NKS - 1)
        MFMASET(A)
        MFMASET(C)

        const int wm = mg0 * 16;
        const int wn = nb * 64;
        const int r0 = (lane >> 4) * 4;
        const int cc = lane & 15;
#pragma unroll
        for (int mi = 0; mi < 2; ++mi)
#pragma unroll
            for (int ni = 0; ni < 4; ++ni)
#pragma unroll
                for (int j = 0; j < 4; ++j)
                    tbuf[(size_t)(wm + mi * 16 + r0 + j) * HH + wn + ni * 16 + cc] =
                        acc[mi][ni][j];
    } else {
        // -------- combine segmean partials + LN(g2,b2) --------
        const int cb = blockIdx.x - NGB;
        const int t = threadIdx.x;
        const int lane = t & 63, wv = t >> 6;
        const int s0 = gstart[cb], e0 = gend[cb];
        const float inv = 1.0f / fmaxf((float)(e0 - s0), 1.0f);

        float v[6];
#pragma unroll
        for (int j = 0; j < 6; ++j) v[j] = 0.f;
        const float* base = pp + (size_t)cb * SEG_SLICES * HH;
#pragma unroll
        for (int sl = 0; sl < SEG_SLICES; ++sl) {
#pragma unroll
            for (int j = 0; j < 6; ++j)
                v[j] += base[(size_t)sl * HH + t + 128 * j];
        }
        float s = 0.f, q = 0.f;
#pragma unroll
        for (int j = 0; j < 6; ++j) {
            v[j] *= inv;
            s += v[j];
            q = fmaf(v[j], v[j], q);
        }
        for (int o = 32; o > 0; o >>= 1) {
            s += __shfl_xor(s, o, 64);
            q += __shfl_xor(q, o, 64);
        }
        if (lane == 0) { red[0][wv] = s; red[1][wv] = q; }
        __syncthreads();
        if (t == 0) {
            const float ts = red[0][0] + red[0][1];
            const float tq = red[1][0] + red[1][1];
            const float mu = ts / (float)HH;
            const float var = tq / (float)HH - mu * mu;
            sh2[0] = mu;
            sh2[1] = rsqrtf(var + EPS_LN);
        }
        __syncthreads();
        const float mu = sh2[0], rinv = sh2[1];
        float n = 0.f;
#pragma unroll
        for (int j = 0; j < 6; ++j) {
            const int c = t + 128 * j;
            const float y = (v[j] - mu) * rinv * g2[c] + b2[c];
            sel[(size_t)cb * HH + c] = y;
            n = fmaf(y, y, n);
        }
        for (int o = 32; o > 0; o >>= 1) n += __shfl_xor(n, o, 64);
        if (lane == 0) red2[wv] = n;
        __syncthreads();
        if (t == 0) selnorm[cb] = sqrtf(red2[0] + red2[1]);
    }
}

// K3: per-row LN(g1,b1) + cosine vs sel. One wave per t-row; bias folded in.
__global__ __launch_bounds__(512) void k_finish(
    const float* __restrict__ tbuf, const float* __restrict__ bias,
    const float* __restrict__ g1, const float* __restrict__ b1,
    const float* __restrict__ sel, const float* __restrict__ selnorm,
    float* __restrict__ out)
{
    const int lane = threadIdx.x & 63;
    const int w = threadIdx.x >> 6;
    const int m = blockIdx.x * 8 + w;
    const int b = m >> 5;
    const float* trow = tbuf + (size_t)m * HH;

    float v[12];
#pragma unroll
    for (int j = 0; j < 12; ++j) {
        const int col = lane + 64 * j;
        v[j] = trow[col] + bias[col];
    }
    float s = 0.f, q = 0.f;
#pragma unroll
    for (int j = 0; j < 12; ++j) { s += v[j]; q = fmaf(v[j], v[j], q); }
    for (int o = 32; o > 0; o >>= 1) {
        s += __shfl_xor(s, o, 64);
        q += __shfl_xor(q, o, 64);
    }
    const float mu = s * (1.0f / (float)HH);
    const float var = q * (1.0f / (float)HH) - mu * mu;
    const float rinv = rsqrtf(var + EPS_LN);

    const float* selb = sel + (size_t)b * HH;
    float d = 0.f, n2 = 0.f;
#pragma unroll
    for (int j = 0; j < 12; ++j) {
        const int col = lane + 64 * j;
        const float y = (v[j] - mu) * rinv * g1[col] + b1[col];
        d = fmaf(y, selb[col], d);
        n2 = fmaf(y, y, n2);
    }
    for (int o = 32; o > 0; o >>= 1) {
        d += __shfl_xor(d, o, 64);
        n2 += __shfl_xor(n2, o, 64);
    }
    if (lane == 0)
        out[m] = d / fmaxf(selnorm[b] * sqrtf(n2), EPS_COS);
}

extern "C" void kernel_launch(void* const* d_in, const int* in_sizes, int n_in,
                              void* d_out, int out_size, void* d_ws, size_t ws_size,
                              hipStream_t stream) {
    const float* hs  = (const float*)d_in[0];
    const float* gp  = (const float*)d_in[1];
    const float* W   = (const float*)d_in[2];
    const float* bia = (const float*)d_in[3];
    const float* g1  = (const float*)d_in[4];
    const float* b1  = (const float*)d_in[5];
    const float* g2  = (const float*)d_in[6];
    const float* b2  = (const float*)d_in[7];
    const int* gs    = (const int*)d_in[8];
    const int* ge    = (const int*)d_in[9];
    float* out = (float*)d_out;

    char* ws = (char*)d_ws;
    short8* a_ws  = (short8*)ws;                                    // 6.29 MB
    short8* b_ws  = (short8*)(ws + (size_t)A_RG * CH_PER_G * 16);   // 2.36 MB
    float* tbuf   = (float*)(ws + (size_t)(A_RG + B_RG) * CH_PER_G * 16); // 6.29 MB
    float* pp      = tbuf + (size_t)MM * HH;                        // 1.57 MB
    float* sel     = pp + (size_t)BB * SEG_SLICES * HH;
    float* selnorm = sel + (size_t)BB * HH;

    k_prep<<<SEG_BLK + A_RG + B_RG, 256, 0, stream>>>(gp, W, hs, gs, ge,
                                                      a_ws, b_ws, pp);
    k_gemm<<<NGB + BB, 128, 0, stream>>>(a_ws, b_ws, pp, g2, b2, gs, ge,
                                         tbuf, sel, selnorm);
    k_finish<<<MM / 8, 512, 0, stream>>>(tbuf, bia, g1, b1, sel, selnorm, out);
}